// Round 13
// baseline (51.529 us; speedup 1.0000x reference)
//
#include <hip/hip_runtime.h>

// Problem: x [B=64, C=512, H=28, W=28] fp32.
// Forward math reduces to: out = relu(x - mean_over_C(x)) per (b,h,w).
//
// Round-12 (resubmit; container unresponsive): CONTIGUOUS-WAVE restructure.
// All previous kernels put the C-reduction across lanes -> every wave VMEM
// instruction touched 4-8 disjoint 128-256B segments, sustaining only
// ~4-5 TB/s while the harness's own fillBuffer sustains 6.8 TB/s on this
// chip. Here lanes = 64 consecutive float4 positions (one contiguous 1KB
// segment per wave load/store, the copy/fill pattern) and the C-reduction
// is a lane-local loop over the wave's 32 channels (uniform stride ->
// SGPR-increment address loop).
//   block = 1024 thr = 16 waves; wave w owns channels [32w, 32w+32);
//   lane l owns flat group blockIdx*64+l  (12544 groups = 196 blocks exact).
//   Pass1: 32 contiguous 1KB wave-loads, lane-local f4 accumulation.
//   Combine: 16 wave-partials in LDS, 1 barrier, lane-local mean.
//   Pass2: re-read same 32 lines (L2/LLC-hot), subtract, relu, nt-store.
// HBM traffic unchanged (~164 MB); the re-read is cache-served. If the
// contiguity theory is right this runs at copy-rate; if flat, we are at the
// op's structural ceiling.

#define B_DIM 64
#define C_DIM 512
#define HW4   196               // 28*28/4 float4 groups per (b,c) plane
#define TILE  64                // float4-groups per block (one per lane)
#define NW    16                // waves per block (1024 threads)
#define CPW   (C_DIM / NW)      // 32 channels per wave

typedef __attribute__((ext_vector_type(4))) float f4;

__global__ __launch_bounds__(1024) void kwinners_fwd(const float* __restrict__ x,
                                                     float* __restrict__ out) {
    __shared__ f4 part[NW][TILE];       // 16 KB

    const int tid  = threadIdx.x;
    const int lane = tid & 63;
    const int wv   = tid >> 6;          // 0..15

    const int g   = blockIdx.x * TILE + lane;   // flat float4-group id
    const int b   = g / HW4;
    const int hw4 = g - b * HW4;

    // group offset of (b, c = wv*CPW, hw4); per-iteration stride = HW4 groups
    const size_t base = (size_t)b * C_DIM * HW4 + (size_t)(wv * CPW) * HW4 + hw4;
    const f4* __restrict__ xp = reinterpret_cast<const f4*>(x) + base;
    f4* __restrict__ op       = reinterpret_cast<f4*>(out) + base;

    // ---- pass 1: lane-local channel accumulation, contiguous wave loads ----
    f4 s = (f4)(0.0f);
    #pragma unroll 8
    for (int cc = 0; cc < CPW; ++cc)
        s += xp[(size_t)cc * HW4];

    // ---- combine the 16 per-wave partials (one barrier) ----
    part[wv][lane] = s;
    __syncthreads();

    f4 m = (f4)(0.0f);
    #pragma unroll
    for (int ww = 0; ww < NW; ++ww) m += part[ww][lane];
    m *= (1.0f / (float)C_DIM);

    // ---- pass 2: re-read (L2/LLC-hot), subtract, relu, nt contiguous store ----
    #pragma unroll 8
    for (int cc = 0; cc < CPW; ++cc) {
        f4 v = xp[(size_t)cc * HW4];
        f4 r = v - m;
        r.x = fmaxf(r.x, 0.f);
        r.y = fmaxf(r.y, 0.f);
        r.z = fmaxf(r.z, 0.f);
        r.w = fmaxf(r.w, 0.f);
        __builtin_nontemporal_store(r, &op[(size_t)cc * HW4]);
    }
}

extern "C" void kernel_launch(void* const* d_in, const int* in_sizes, int n_in,
                              void* d_out, int out_size, void* d_ws, size_t ws_size,
                              hipStream_t stream) {
    const float* x  = (const float*)d_in[0];   // [B, C, H, W] fp32
    float* out = (float*)d_out;

    const int groups = B_DIM * HW4;            // 12544 float4 groups
    dim3 grid(groups / TILE);                  // 196 blocks, exact
    dim3 block(1024);                          // 16 waves
    hipLaunchKernelGGL(kwinners_fwd, grid, block, 0, stream, x, out);
}

// Round 14
// 39.216 us; speedup vs baseline: 1.3140x; 1.3140x over previous
//
#include <hip/hip_runtime.h>

// Problem: x [B=64, C=512, H=28, W=28] fp32.
// Forward math reduces to: out = relu(x - mean_over_C(x)) per (b,h,w).
//
// Round-14: 512B-segment ladder point. Request-rate model from rounds 1-13:
// time = total request bytes / rate(segment width); measured rates:
// 128B->4.03, 256B->5.06, 1KB contiguous->5.94 TB/s. Two-pass contiguous
// loses (306 MB requests); strided ~single-pass is 203 MB. This round: TX=32
// -> each wave VMEM instruction covers two 512B contiguous segments.
// Single variable vs round 8 (TX=16, 40.63us): block 256->512, TX 16->32.
//  - TY=16, CPT=32 (compiler remat -> L2-served second read, priced in)
//  - nt stores (best known), 1 barrier, shuffle+LDS combine

#define B_DIM 64
#define C_DIM 512
#define HW4   196               // 28*28/4 float4 groups per (b,c) plane
#define TX    32                // float4-groups per block (512B segments)
#define TY    16                // channel slices
#define CPT   (C_DIM / TY)      // 32 channels per thread
#define NW    8                 // waves per block (512 threads)

typedef __attribute__((ext_vector_type(4))) float f4;

__global__ __launch_bounds__(512) void kwinners_fwd(const float* __restrict__ x,
                                                    float* __restrict__ out) {
    __shared__ f4 part[NW][TX];     // 4 KB

    const int tid = threadIdx.x;
    const int tx  = tid & (TX - 1);     // 0..31
    const int ty  = tid >> 5;           // 0..15
    const int w   = tid >> 6;           // wave id 0..7

    const int g   = blockIdx.x * TX + tx;   // global float4-group index
    const int b   = g / HW4;
    const int hw4 = g - b * HW4;

    const f4* __restrict__ xb =
        reinterpret_cast<const f4*>(x) + (size_t)b * C_DIM * HW4 + hw4;
    f4* __restrict__ ob =
        reinterpret_cast<f4*>(out) + (size_t)b * C_DIM * HW4 + hw4;

    const int c0 = ty * CPT;

    // ---- read: 32 float4 per thread (compiler may remat for store phase) ----
    f4 v[CPT];
    #pragma unroll
    for (int cc = 0; cc < CPT; ++cc) {
        v[cc] = xb[(c0 + cc) * HW4];
    }

    // ---- per-thread partial sum ----
    f4 s = (f4)(0.0f);
    #pragma unroll
    for (int cc = 0; cc < CPT; ++cc) s += v[cc];

    // ---- wave-level reduce: lanes sharing tx differ in tid bit 5 only ----
    s.x += __shfl_xor(s.x, 32);
    s.y += __shfl_xor(s.y, 32);
    s.z += __shfl_xor(s.z, 32);
    s.w += __shfl_xor(s.w, 32);

    // ---- combine the 8 per-wave partials (one barrier) ----
    if ((tid & 63) < TX) part[w][tx] = s;
    __syncthreads();

    f4 m4 = (f4)(0.0f);
    #pragma unroll
    for (int ww = 0; ww < NW; ++ww) m4 += part[ww][tx];
    m4 *= (1.0f / (float)C_DIM);

    // ---- store relu(v - mean), non-temporal ----
    #pragma unroll
    for (int cc = 0; cc < CPT; ++cc) {
        f4 r = v[cc] - m4;
        r.x = fmaxf(r.x, 0.f);
        r.y = fmaxf(r.y, 0.f);
        r.z = fmaxf(r.z, 0.f);
        r.w = fmaxf(r.w, 0.f);
        __builtin_nontemporal_store(r, &ob[(c0 + cc) * HW4]);
    }
}

extern "C" void kernel_launch(void* const* d_in, const int* in_sizes, int n_in,
                              void* d_out, int out_size, void* d_ws, size_t ws_size,
                              hipStream_t stream) {
    const float* x  = (const float*)d_in[0];   // [B, C, H, W] fp32
    float* out = (float*)d_out;

    const int groups = B_DIM * HW4;            // 12544 float4 groups
    dim3 grid(groups / TX);                    // 392 blocks x 8 waves
    dim3 block(512);
    hipLaunchKernelGGL(kwinners_fwd, grid, block, 0, stream, x, out);
}